// Round 1
// baseline (70.446 us; speedup 1.0000x reference)
//
#include <hip/hip_runtime.h>

#define N_CP   128
#define N_DATA 32768
#define BATCH  16
#define DIM    3

// One thread per (b, n-group-of-4). Exploits the 5-wide band structure of the
// NURBS basis matrix: column n is nonzero only on rows [span-4, span],
// span = clip(4 + floor(124*n/32767), 4, 127).
//
// For a group of 4 consecutive columns starting at n0:
//   - span grows by at most 1 across the group (3*124/32767 << 1)
//   - fp32 rounding vs the reference's float64 searchsorted adds +/-1 margin
// so the union of all nonzero rows lies within [span(n0)-5, span(n0)+2]:
// an 8-row window. Out-of-band entries are exactly 0.0f and contribute
// nothing, so over-reading is harmless.
//
// Memory shape: each row read is a global_load_dwordx4 (16 B/lane, 1 KiB/wave,
// the coalescing sweet spot), 8 independent loads of ILP per thread; the
// three output rows are global_store_dwordx4. This replaces the previous
// version's 28 scalar loads + 12 scalar stores per 4 columns.
__global__ __launch_bounds__(256) void nurbs_band4_kernel(
    const float* __restrict__ cp,    // [BATCH, DIM, N_CP]
    const float* __restrict__ w,     // [BATCH, 1, N_CP]
    const float* __restrict__ Nmat,  // [N_CP, N_DATA]
    float* __restrict__ out)         // [BATCH, DIM, N_DATA]
{
    __shared__ float w_l[N_CP];
    __shared__ float cw_l[DIM][N_CP];

    const int tid = blockIdx.x * 256 + threadIdx.x;
    const int b  = tid >> 13;            // 8192 groups per batch; block is single-b
    const int n0 = (tid & 8191) << 2;    // first of 4 consecutive columns

    // Stage w[b,:] and cw[d][c] = cp[b,d,c]*w[b,c] into LDS (2 KB).
    const int t = threadIdx.x;
    if (t < N_CP) {
        float wv = w[b * N_CP + t];
        w_l[t] = wv;
#pragma unroll
        for (int d = 0; d < DIM; ++d)
            cw_l[d][t] = cp[(b * DIM + d) * N_CP + t] * wv;
    }
    __syncthreads();

    // Band window: rows lo..lo+7 cover all nonzeros of columns n0..n0+3.
    float x = (float)n0 * (124.0f / 32767.0f);
    int span = 4 + (int)x;               // x >= 0, (int) == floor
    if (span > 127) span = 127;
    int lo = span - 5;
    if (lo < 0)   lo = 0;
    if (lo > 120) lo = 120;              // keep lo+7 <= 127

    float4 W  = make_float4(0.f, 0.f, 0.f, 0.f);
    float4 s0 = make_float4(0.f, 0.f, 0.f, 0.f);
    float4 s1 = make_float4(0.f, 0.f, 0.f, 0.f);
    float4 s2 = make_float4(0.f, 0.f, 0.f, 0.f);

#pragma unroll
    for (int r = 0; r < 8; ++r) {
        const int c = lo + r;
        const float4 Nv = *reinterpret_cast<const float4*>(
            Nmat + (size_t)c * N_DATA + n0);          // dwordx4, coalesced
        const float wc = w_l[c];                       // (near-)broadcast reads
        const float c0 = cw_l[0][c];
        const float c1 = cw_l[1][c];
        const float c2 = cw_l[2][c];
        W.x  = fmaf(wc, Nv.x, W.x);  W.y  = fmaf(wc, Nv.y, W.y);
        W.z  = fmaf(wc, Nv.z, W.z);  W.w  = fmaf(wc, Nv.w, W.w);
        s0.x = fmaf(c0, Nv.x, s0.x); s0.y = fmaf(c0, Nv.y, s0.y);
        s0.z = fmaf(c0, Nv.z, s0.z); s0.w = fmaf(c0, Nv.w, s0.w);
        s1.x = fmaf(c1, Nv.x, s1.x); s1.y = fmaf(c1, Nv.y, s1.y);
        s1.z = fmaf(c1, Nv.z, s1.z); s1.w = fmaf(c1, Nv.w, s1.w);
        s2.x = fmaf(c2, Nv.x, s2.x); s2.y = fmaf(c2, Nv.y, s2.y);
        s2.z = fmaf(c2, Nv.z, s2.z); s2.w = fmaf(c2, Nv.w, s2.w);
    }

    const float4 inv = make_float4(1.0f / W.x, 1.0f / W.y,
                                   1.0f / W.z, 1.0f / W.w);

    float* ob = out + (size_t)b * (DIM * N_DATA) + n0;
    *reinterpret_cast<float4*>(ob) =
        make_float4(s0.x * inv.x, s0.y * inv.y, s0.z * inv.z, s0.w * inv.w);
    *reinterpret_cast<float4*>(ob + N_DATA) =
        make_float4(s1.x * inv.x, s1.y * inv.y, s1.z * inv.z, s1.w * inv.w);
    *reinterpret_cast<float4*>(ob + 2 * N_DATA) =
        make_float4(s2.x * inv.x, s2.y * inv.y, s2.z * inv.z, s2.w * inv.w);
}

extern "C" void kernel_launch(void* const* d_in, const int* in_sizes, int n_in,
                              void* d_out, int out_size, void* d_ws, size_t ws_size,
                              hipStream_t stream) {
    // d_in[0] = input (unused by reference), d_in[1] = control_points,
    // d_in[2] = weights, d_in[3] = N
    const float* cp   = (const float*)d_in[1];
    const float* w    = (const float*)d_in[2];
    const float* Nmat = (const float*)d_in[3];
    float* out = (float*)d_out;

    const int total_groups = BATCH * (N_DATA / 4);   // 131072 threads
    const int blocks = total_groups / 256;           // 512 blocks
    nurbs_band4_kernel<<<blocks, 256, 0, stream>>>(cp, w, Nmat, out);
}